// Round 5
// baseline (167.174 us; speedup 1.0000x reference)
//
#include <hip/hip_runtime.h>
#include <stdint.h>

// PercolationQ: per-patch occupancy fraction -> threshold -> mean over patches.
// R1/R2/R4 all plateau at ~52us, ~2.8 TB/s effective input BW, with ~1-2 loads
// in flight per lane (VGPR_Count 24-28: compiler software-pipelines away the
// batch). This version FORCES 16 global_load_dwordx4 in flight per lane via
// inline asm + explicit s_waitcnt, decoupling MLP from compiler heuristics.
//
// Layout: every (c,b) row = 65536 floats = 256 KB, identical for all 3 inputs.
// Block = 256 thr = quarter row (16384 floats); thread = 256 B contiguous
// (16 float4 = 64 floats). 2304 blocks = 9.00 per CU (exact balance).
//   x4 : 64 floats = 4 patches  (sums of v0..3 / v4..7 / v8..11 / v12..15)
//   x8 : 64 floats = 1 patch    (total sum)
//   x16: 4 threads = 1 patch    (shfl_xor 1,2 across lane quads)
// 4 blocks per row -> atomicAdd of exact dyadic partials (k * 2^-12 etc.).
// out: 576 floats = [q4(192) | q8(192) | q16(192)], row-major [c*64+b].

#define PERC_THRESHOLD 0.59275f

typedef float f4v __attribute__((ext_vector_type(4)));

__global__ __launch_bounds__(256)
void PercolationQ_31885837205970_kernel(const float* __restrict__ x4,
                                        const float* __restrict__ x8,
                                        const float* __restrict__ x16,
                                        float* __restrict__ out) {
    const int bx = blockIdx.x;
    const int tid = threadIdx.x;
    const int lane = tid & 63;

    const float* base;
    int type, row;
    float* o;
    float invP;

    if (bx < 768) {                 // x16
        base = x16;  type = 2;  row = bx >> 2;
        o = out + 384; invP = 1.0f / 256.0f;
        base += ((size_t)bx << 14);
    } else if (bx < 1536) {         // x8
        int b = bx - 768;
        base = x8;   type = 1;  row = b >> 2;
        o = out + 192; invP = 1.0f / 1024.0f;
        base += ((size_t)b << 14);
    } else {                        // x4
        int b = bx - 1536;
        base = x4;   type = 0;  row = b >> 2;
        o = out;       invP = 1.0f / 4096.0f;
        base += ((size_t)b << 14);
    }

    // per-thread 256 B contiguous chunk
    uint64_t addr = (uint64_t)(base + (tid << 6));

    f4v v0, v1, v2, v3, v4, v5, v6, v7, v8, v9, v10, v11, v12, v13, v14, v15;
    // 16 loads issued back-to-back: guaranteed 16 outstanding per lane.
    asm volatile("global_load_dwordx4 %0, %1, off            " : "=v"(v0)  : "v"(addr));
    asm volatile("global_load_dwordx4 %0, %1, off offset:16  " : "=v"(v1)  : "v"(addr));
    asm volatile("global_load_dwordx4 %0, %1, off offset:32  " : "=v"(v2)  : "v"(addr));
    asm volatile("global_load_dwordx4 %0, %1, off offset:48  " : "=v"(v3)  : "v"(addr));
    asm volatile("global_load_dwordx4 %0, %1, off offset:64  " : "=v"(v4)  : "v"(addr));
    asm volatile("global_load_dwordx4 %0, %1, off offset:80  " : "=v"(v5)  : "v"(addr));
    asm volatile("global_load_dwordx4 %0, %1, off offset:96  " : "=v"(v6)  : "v"(addr));
    asm volatile("global_load_dwordx4 %0, %1, off offset:112 " : "=v"(v7)  : "v"(addr));
    asm volatile("global_load_dwordx4 %0, %1, off offset:128 " : "=v"(v8)  : "v"(addr));
    asm volatile("global_load_dwordx4 %0, %1, off offset:144 " : "=v"(v9)  : "v"(addr));
    asm volatile("global_load_dwordx4 %0, %1, off offset:160 " : "=v"(v10) : "v"(addr));
    asm volatile("global_load_dwordx4 %0, %1, off offset:176 " : "=v"(v11) : "v"(addr));
    asm volatile("global_load_dwordx4 %0, %1, off offset:192 " : "=v"(v12) : "v"(addr));
    asm volatile("global_load_dwordx4 %0, %1, off offset:208 " : "=v"(v13) : "v"(addr));
    asm volatile("global_load_dwordx4 %0, %1, off offset:224 " : "=v"(v14) : "v"(addr));
    asm volatile("global_load_dwordx4 %0, %1, off offset:240 " : "=v"(v15) : "v"(addr));
    // Single wait; "+v" redefines every payload so no consumer can be hoisted
    // above this point by the scheduler.
    asm volatile("s_waitcnt vmcnt(0)"
                 : "+v"(v0), "+v"(v1), "+v"(v2), "+v"(v3),
                   "+v"(v4), "+v"(v5), "+v"(v6), "+v"(v7),
                   "+v"(v8), "+v"(v9), "+v"(v10), "+v"(v11),
                   "+v"(v12), "+v"(v13), "+v"(v14), "+v"(v15));

    const float s0  = (v0.x + v0.y) + (v0.z + v0.w);
    const float s1  = (v1.x + v1.y) + (v1.z + v1.w);
    const float s2  = (v2.x + v2.y) + (v2.z + v2.w);
    const float s3  = (v3.x + v3.y) + (v3.z + v3.w);
    const float s4  = (v4.x + v4.y) + (v4.z + v4.w);
    const float s5  = (v5.x + v5.y) + (v5.z + v5.w);
    const float s6  = (v6.x + v6.y) + (v6.z + v6.w);
    const float s7  = (v7.x + v7.y) + (v7.z + v7.w);
    const float s8  = (v8.x + v8.y) + (v8.z + v8.w);
    const float s9  = (v9.x + v9.y) + (v9.z + v9.w);
    const float s10 = (v10.x + v10.y) + (v10.z + v10.w);
    const float s11 = (v11.x + v11.y) + (v11.z + v11.w);
    const float s12 = (v12.x + v12.y) + (v12.z + v12.w);
    const float s13 = (v13.x + v13.y) + (v13.z + v13.w);
    const float s14 = (v14.x + v14.y) + (v14.z + v14.w);
    const float s15 = (v15.x + v15.y) + (v15.z + v15.w);

    int cnt = 0;
    if (type == 0) {               // x4: 4 patches of 16 floats
        float p0 = (s0 + s1) + (s2 + s3);
        float p1 = (s4 + s5) + (s6 + s7);
        float p2 = (s8 + s9) + (s10 + s11);
        float p3 = (s12 + s13) + (s14 + s15);
        cnt = (p0 * (1.0f / 16.0f) >= PERC_THRESHOLD)
            + (p1 * (1.0f / 16.0f) >= PERC_THRESHOLD)
            + (p2 * (1.0f / 16.0f) >= PERC_THRESHOLD)
            + (p3 * (1.0f / 16.0f) >= PERC_THRESHOLD);
    } else {
        float t = (((s0 + s1) + (s2 + s3)) + ((s4 + s5) + (s6 + s7)))
                + (((s8 + s9) + (s10 + s11)) + ((s12 + s13) + (s14 + s15)));
        if (type == 1) {           // x8: thread = 1 patch
            cnt = (t * (1.0f / 64.0f) >= PERC_THRESHOLD);
        } else {                   // x16: 4 consecutive lanes = 1 patch
            float a = t + __shfl_xor(t, 1, 64);
            a += __shfl_xor(a, 2, 64);
            cnt = ((lane & 3) == 0) && (a * (1.0f / 256.0f) >= PERC_THRESHOLD);
        }
    }

    // block reduction: wave shfl tree -> LDS -> one atomic per block
#pragma unroll
    for (int off = 32; off > 0; off >>= 1)
        cnt += __shfl_down(cnt, off, 64);

    __shared__ int wsum[4];
    if (lane == 0) wsum[tid >> 6] = cnt;
    __syncthreads();
    if (tid == 0) {
        float total = (float)(wsum[0] + wsum[1] + wsum[2] + wsum[3]);
        atomicAdd(&o[row], total * invP);   // dyadic partials -> exact sum
    }
}

extern "C" void kernel_launch(void* const* d_in, const int* in_sizes, int n_in,
                              void* d_out, int out_size, void* d_ws, size_t ws_size,
                              hipStream_t stream) {
    const float* x4  = (const float*)d_in[0];
    const float* x8  = (const float*)d_in[1];
    const float* x16 = (const float*)d_in[2];
    float* out = (float*)d_out;

    // d_out is re-poisoned to 0xAA before every launch; atomics accumulate.
    hipMemsetAsync(d_out, 0, (size_t)out_size * sizeof(float), stream);

    dim3 grid(2304), block(256);   // 9.00 blocks per CU, exact balance
    hipLaunchKernelGGL(PercolationQ_31885837205970_kernel, grid, block, 0, stream,
                       x4, x8, x16, out);
}